// Round 14
// baseline (181.517 us; speedup 1.0000x reference)
//
#include <hip/hip_runtime.h>
#include <hip/hip_bf16.h>
#include <math.h>

#define N_NODES 50000
#define N_EDGES 800000
#define GEMM_ROWS 32
#define AGG_NODES 32
#define PAD_EDGES (N_EDGES + N_NODES * 15)  // segments padded to x16
#define QGEMM_BLOCKS ((N_NODES + GEMM_ROWS - 1) / GEMM_ROWS)  // 1563
#define BASE_BLOCKS ((N_NODES + 255) / 256)                    // 196
// 0.125 (1/sqrt(64)) * log2(e): folded into Wt -> exp2 in the hot loop.
#define SCALE_FOLD 0.18033688011112042f
// u32 per LDS x-row; row pitch must be 16B-multiple for uint4 stores: 36*4=144.
#define XT_STRIDE 36

typedef __attribute__((ext_vector_type(8))) short bf16x8_t;
typedef __attribute__((ext_vector_type(4))) float f32x4_t;

static __device__ __forceinline__ ushort bfrn(float v) {
  __hip_bfloat16 b = __float2bfloat16(v);  // round-to-nearest-even
  return __builtin_bit_cast(ushort, b);
}
static __device__ __forceinline__ bf16x8_t as_bf16x8(uint4 u) {
  union { uint4 a; bf16x8_t b; } c; c.a = u; return c.b;
}
static __device__ __forceinline__ float bflo(uint u) {
  return __uint_as_float(u << 16);
}
static __device__ __forceinline__ float bfhi(uint u) {
  return __uint_as_float(u & 0xFFFF0000u);
}

// ---------------------------------------------------------------------------
// K1: hist (degree + intra-segment position) + fused W_att^T transpose/scale.
// Wt[h*4096 + r*64 + c] = Watt[c*256 + h*64 + r] * SCALE_FOLD
// => q_t[i][h][c] = sum_r x_i[r]*Watt[c][h*64+r];  score = u[src].x[dst].
// ---------------------------------------------------------------------------
__global__ __launch_bounds__(256) void hist_kernel(
    const int* __restrict__ dst, int* __restrict__ deg, int* __restrict__ epos,
    const float* __restrict__ Watt, float* __restrict__ Wt) {
  int e = blockIdx.x * 256 + threadIdx.x;
  if (e < 16384) {
    int c = e & 63;
    int r = (e >> 6) & 63;
    int h = e >> 12;
    Wt[e] = Watt[c * 256 + h * 64 + r] * SCALE_FOLD;
  }
  if (e < N_EDGES) epos[e] = atomicAdd(&deg[dst[e]], 1);
}

// ---------------------------------------------------------------------------
// K2 (merged): qgemm tiles + per-node CSR base (wave-aggregated atomic).
// ---------------------------------------------------------------------------
__global__ __launch_bounds__(256) void qgemm_base_kernel(
    const float* __restrict__ x, const float* __restrict__ Wt,
    uint2* __restrict__ q_t2, ushort* __restrict__ xhi,
    const int* __restrict__ deg, int* __restrict__ cursor,
    int2* __restrict__ offs2, int2* __restrict__ csr2) {
  const int tid = threadIdx.x;
  if (blockIdx.x >= QGEMM_BLOCKS) {
    const int i = (blockIdx.x - QGEMM_BLOCKS) * 256 + tid;
    const int lane = tid & 63;
    const int d = (i < N_NODES) ? deg[i] : 0;
    const int nt = (d + 15) >> 4;
    const int pd = nt << 4;
    int incl = pd;
#pragma unroll
    for (int m = 1; m < 64; m <<= 1) {
      int u = __shfl_up(incl, m);
      if (lane >= m) incl += u;
    }
    int wbase = 0;
    if (lane == 63) wbase = atomicAdd(cursor, incl);
    wbase = __shfl(wbase, 63);
    const int base = wbase + incl - pd;
    if (i < N_NODES) {
      offs2[i] = make_int2(base, nt);
      for (int j = d; j < pd; ++j) csr2[base + j] = make_int2(0, 0);
    }
    return;
  }
  __shared__ float xlds[GEMM_ROWS * 64];
  const int blk = blockIdx.x;
#pragma unroll
  for (int p = 0; p < 8; ++p) {
    int idx = p * 256 + tid;
    int gidx = blk * (GEMM_ROWS * 64) + idx;
    xlds[idx] = (gidx < N_NODES * 64) ? x[gidx] : 0.f;
  }
  __syncthreads();
  {
    int row = tid >> 3;
    int c0 = (tid & 7) * 8;
    int grow = blk * GEMM_ROWS + row;
    if (grow < N_NODES) {
      uint hu[4];
#pragma unroll
      for (int d2 = 0; d2 < 4; ++d2) {
        float v0 = xlds[row * 64 + c0 + 2 * d2];
        float v1 = xlds[row * 64 + c0 + 2 * d2 + 1];
        hu[d2] = (uint)bfrn(v0) | ((uint)bfrn(v1) << 16);
      }
      *(uint4*)(xhi + (size_t)grow * 64 + c0) =
          make_uint4(hu[0], hu[1], hu[2], hu[3]);
    }
  }
  const int c4 = tid & 63;
  const int h = c4 >> 4;
  const int f4 = c4 & 15;
  const int rg = (tid >> 6) * 8;
  const float4* Wv = (const float4*)Wt;
  float4 acc[8] = {};
  for (int g = 0; g < 64; ++g) {
    float4 w4 = Wv[(size_t)h * 1024 + g * 16 + f4];
#pragma unroll
    for (int r = 0; r < 8; ++r) {
      float a = xlds[(rg + r) * 64 + g];
      acc[r].x += a * w4.x; acc[r].y += a * w4.y;
      acc[r].z += a * w4.z; acc[r].w += a * w4.w;
    }
  }
#pragma unroll
  for (int r = 0; r < 8; ++r) {
    int row = blk * GEMM_ROWS + rg + r;
    if (row < N_NODES) {
      uint2 pk;
      pk.x = (uint)bfrn(acc[r].x) | ((uint)bfrn(acc[r].y) << 16);
      pk.y = (uint)bfrn(acc[r].z) | ((uint)bfrn(acc[r].w) << 16);
      q_t2[(size_t)row * 64 + c4] = pk;  // ushort[row*256 + h*64 + 4f4..]
    }
  }
}

// ---------------------------------------------------------------------------
// K3: scatter edges into padded-CSR order (no atomics; single 8B write)
// ---------------------------------------------------------------------------
__global__ __launch_bounds__(256) void scatter_kernel(
    const int* __restrict__ src, const int* __restrict__ dst,
    const float* __restrict__ ew, const int2* __restrict__ offs2,
    const int* __restrict__ epos, int2* __restrict__ csr2) {
  int e = blockIdx.x * 256 + threadIdx.x;
  if (e >= N_EDGES) return;
  int idx = offs2[dst[e]].x + epos[e];
  csr2[idx] = make_int2(src[e], __float_as_int(ew[e]));
}

// ---------------------------------------------------------------------------
// K4: aggregation, TWO nodes per wave (A,B) with interleaved 16-edge tiles —
// two independent gather->MFMA->exp->PV chains double memory-level
// parallelism (the kernel was latency-bound at 1 node/wave, R11: 46.7us).
// Mismatched tile counts are masked: w=0 kills the contribution; j is
// clamped so a poison read can't fault. Numerics identical to R11.
// ---------------------------------------------------------------------------
__global__ __launch_bounds__(256) void aggregate_kernel(
    const uint4* __restrict__ qt4, const uint4* __restrict__ xhi4,
    const int2* __restrict__ offs2, const int2* __restrict__ csr2,
    ushort* __restrict__ agg) {
  __shared__ __attribute__((aligned(16))) uint xt[4][2][16][XT_STRIDE];
  __shared__ __attribute__((aligned(16))) float plds[4][2][16][4];
  const int wave = threadIdx.x >> 6;
  const int lane = threadIdx.x & 63;
  const int l15 = lane & 15;
  const int lg = lane >> 4;
  const int hq = l15 & 3;
  const int nA = blockIdx.x * 8 + wave * 2;  // grid exact: 6250*8 = 50000
  const int nB = nA + 1;

  const bf16x8_t QaA = as_bf16x8(qt4[(size_t)nA * 32 + hq * 8 + lg]);
  const bf16x8_t QbA = as_bf16x8(qt4[(size_t)nA * 32 + hq * 8 + 4 + lg]);
  const bf16x8_t QaB = as_bf16x8(qt4[(size_t)nB * 32 + hq * 8 + lg]);
  const bf16x8_t QbB = as_bf16x8(qt4[(size_t)nB * 32 + hq * 8 + 4 + lg]);
  const int2 oA = offs2[nA];
  const int2 oB = offs2[nB];
  const int ntmax = (oA.y > oB.y) ? oA.y : oB.y;

  f32x4_t accA = {0.f, 0.f, 0.f, 0.f};
  f32x4_t accB = {0.f, 0.f, 0.f, 0.f};
  float LpA = 0.f, LpB = 0.f;

  for (int t = 0; t < ntmax; ++t) {
    const bool vA = t < oA.y;
    const bool vB = t < oB.y;
    const int kA = oA.x + (vA ? t * 16 : 0) + l15;
    const int kB = oB.x + (vB ? t * 16 : 0) + l15;
    const int2 eA = csr2[kA];
    const int2 eB = csr2[kB];
    const float wAv = vA ? __int_as_float(eA.y) : 0.f;
    const float wBv = vB ? __int_as_float(eB.y) : 0.f;
    const uint jA = min((uint)eA.x, (uint)(N_NODES - 1));
    const uint jB = min((uint)eB.x, (uint)(N_NODES - 1));
    const uint4 a0A = xhi4[(size_t)jA * 8 + lg];
    const uint4 a1A = xhi4[(size_t)jA * 8 + 4 + lg];
    const uint4 a0B = xhi4[(size_t)jB * 8 + lg];
    const uint4 a1B = xhi4[(size_t)jB * 8 + 4 + lg];
    *(uint4*)&xt[wave][0][l15][4 * lg] = a0A;
    *(uint4*)&xt[wave][0][l15][16 + 4 * lg] = a1A;
    *(uint4*)&xt[wave][1][l15][4 * lg] = a0B;
    *(uint4*)&xt[wave][1][l15][16 + 4 * lg] = a1B;
    f32x4_t SA = {0.f, 0.f, 0.f, 0.f};
    f32x4_t SB = {0.f, 0.f, 0.f, 0.f};
    SA = __builtin_amdgcn_mfma_f32_16x16x32_bf16(QaA, as_bf16x8(a0A), SA, 0,
                                                 0, 0);
    SB = __builtin_amdgcn_mfma_f32_16x16x32_bf16(QaB, as_bf16x8(a0B), SB, 0,
                                                 0, 0);
    SA = __builtin_amdgcn_mfma_f32_16x16x32_bf16(QbA, as_bf16x8(a1A), SA, 0,
                                                 0, 0);
    SB = __builtin_amdgcn_mfma_f32_16x16x32_bf16(QbB, as_bf16x8(a1B), SB, 0,
                                                 0, 0);
    float pA0 = exp2f(fmaxf(SA[0], 0.2f * SA[0])) * wAv;
    float pA1 = exp2f(fmaxf(SA[1], 0.2f * SA[1])) * wAv;
    float pA2 = exp2f(fmaxf(SA[2], 0.2f * SA[2])) * wAv;
    float pA3 = exp2f(fmaxf(SA[3], 0.2f * SA[3])) * wAv;
    float pB0 = exp2f(fmaxf(SB[0], 0.2f * SB[0])) * wBv;
    float pB1 = exp2f(fmaxf(SB[1], 0.2f * SB[1])) * wBv;
    float pB2 = exp2f(fmaxf(SB[2], 0.2f * SB[2])) * wBv;
    float pB3 = exp2f(fmaxf(SB[3], 0.2f * SB[3])) * wBv;
    if (lg == 0) {
      *(float4*)&plds[wave][0][l15][0] = make_float4(pA0, pA1, pA2, pA3);
      *(float4*)&plds[wave][1][l15][0] = make_float4(pB0, pB1, pB2, pB3);
    }
#pragma unroll
    for (int e = 0; e < 16; ++e) {
      uint2 xwA = *(const uint2*)&xt[wave][0][e][2 * l15];
      float peA = plds[wave][0][e][lg];
      accA[0] += peA * bflo(xwA.x);
      accA[1] += peA * bfhi(xwA.x);
      accA[2] += peA * bflo(xwA.y);
      accA[3] += peA * bfhi(xwA.y);
      LpA += peA;
      uint2 xwB = *(const uint2*)&xt[wave][1][e][2 * l15];
      float peB = plds[wave][1][e][lg];
      accB[0] += peB * bflo(xwB.x);
      accB[1] += peB * bfhi(xwB.x);
      accB[2] += peB * bflo(xwB.y);
      accB[3] += peB * bfhi(xwB.y);
      LpB += peB;
    }
  }

  const float invA = 1.f / (LpA + 1e-16f);
  const float invB = 1.f / (LpB + 1e-16f);
  uint wa0 = (uint)bfrn(accA[0] * invA) | ((uint)bfrn(accA[1] * invA) << 16);
  uint wa1 = (uint)bfrn(accA[2] * invA) | ((uint)bfrn(accA[3] * invA) << 16);
  uint wb0 = (uint)bfrn(accB[0] * invB) | ((uint)bfrn(accB[1] * invB) << 16);
  uint wb1 = (uint)bfrn(accB[2] * invB) | ((uint)bfrn(accB[3] * invB) << 16);
  *(uint2*)(agg + (size_t)nA * 256 + lg * 64 + l15 * 4) = make_uint2(wa0, wa1);
  *(uint2*)(agg + (size_t)nB * 256 + lg * 64 + l15 * 4) = make_uint2(wb0, wb1);
}

// ---------------------------------------------------------------------------
// K5: out[n, :] = agg(bf16)[n, block-diag] @ Wlin + bias. 32 nodes/block.
// ---------------------------------------------------------------------------
__global__ __launch_bounds__(256) void out_gemm_kernel(
    const ushort* __restrict__ agg, const float* __restrict__ Wlin,
    const float* __restrict__ bias, float* __restrict__ out) {
  __shared__ float4 atile[AGG_NODES][4][17];
  const int tid = threadIdx.x;
  const int node0 = blockIdx.x * AGG_NODES;
  const uint2* av = (const uint2*)agg;
#pragma unroll
  for (int p = 0; p < 8; ++p) {
    int idx = p * 256 + tid;
    int row = idx >> 6;
    int cc = idx & 63;
    if (node0 + row < N_NODES) {
      uint2 u = av[(size_t)(node0 + row) * 64 + cc];
      float4 f;
      f.x = bflo(u.x); f.y = bfhi(u.x);
      f.z = bflo(u.y); f.w = bfhi(u.y);
      atile[row][cc >> 4][cc & 15] = f;
    }
  }
  __syncthreads();
  const int c4 = tid & 63;
  const int ns = tid >> 6;
  const int hh = c4 >> 4;
  const float4* Wv = (const float4*)Wlin;
  float4 acc[8] = {};
  for (int g4 = 0; g4 < 16; ++g4) {
    float4 w0 = Wv[(size_t)(g4 * 4 + 0) * 64 + c4];
    float4 w1 = Wv[(size_t)(g4 * 4 + 1) * 64 + c4];
    float4 w2 = Wv[(size_t)(g4 * 4 + 2) * 64 + c4];
    float4 w3 = Wv[(size_t)(g4 * 4 + 3) * 64 + c4];
#pragma unroll
    for (int n = 0; n < 8; ++n) {
      float4 a = atile[ns * 8 + n][hh][g4];
      acc[n].x += a.x * w0.x + a.y * w1.x + a.z * w2.x + a.w * w3.x;
      acc[n].y += a.x * w0.y + a.y * w1.y + a.z * w2.y + a.w * w3.y;
      acc[n].z += a.x * w0.z + a.y * w1.z + a.z * w2.z + a.w * w3.z;
      acc[n].w += a.x * w0.w + a.y * w1.w + a.z * w2.w + a.w * w3.w;
    }
  }
  float4 bv = ((const float4*)bias)[c4];
#pragma unroll
  for (int n = 0; n < 8; ++n) {
    int node = node0 + ns * 8 + n;
    if (node < N_NODES) {
      float4 o;
      o.x = acc[n].x + bv.x; o.y = acc[n].y + bv.y;
      o.z = acc[n].z + bv.z; o.w = acc[n].w + bv.w;
      ((float4*)out)[(size_t)node * 64 + c4] = o;
    }
  }
}

// ---------------------------------------------------------------------------
extern "C" void kernel_launch(void* const* d_in, const int* in_sizes, int n_in,
                              void* d_out, int out_size, void* d_ws,
                              size_t ws_size, hipStream_t stream) {
  (void)in_sizes; (void)n_in; (void)out_size; (void)ws_size;
  const float* x    = (const float*)d_in[0];
  const int*   ei   = (const int*)d_in[1];
  const float* ew   = (const float*)d_in[2];
  const float* Wlin = (const float*)d_in[3];
  const float* Watt = (const float*)d_in[4];
  const float* bias = (const float*)d_in[5];
  float* out = (float*)d_out;

  const int* srcv = ei;
  const int* dstv = ei + N_EDGES;

  char* ws = (char*)d_ws;
  size_t off = 0;
  auto alloc = [&](size_t bytes) {
    void* p = ws + off;
    off += (bytes + 255) & ~(size_t)255;
    return p;
  };
  ushort* q_t   = (ushort*)alloc((size_t)N_NODES * 256 * 2);  // 25.6 MB
  ushort* agg   = (ushort*)alloc((size_t)N_NODES * 256 * 2);  // 25.6 MB
  ushort* xhi   = (ushort*)alloc((size_t)N_NODES * 64 * 2);   // 6.4 MB
  int2*   offs2 = (int2*)alloc((size_t)N_NODES * 8);          // 0.4 MB
  int2*   csr2  = (int2*)alloc((size_t)PAD_EDGES * 8);        // 12.4 MB
  // aliases inside agg (all dead before aggregate_kernel writes agg):
  char* aggc = (char*)agg;
  int*   deg    = (int*)aggc;                       // 200 KB (dead after base)
  int*   cursor = (int*)(aggc + N_NODES * 4);       // 4 B    (dead after base)
  int*   epos   = (int*)(aggc + 256 * 1024);        // 3.2 MB (dead after scatter)
  float* Wt     = (float*)(aggc + 4 * 1024 * 1024); // 64 KB  (dead after qgemm)

  hipMemsetAsync(deg, 0, (size_t)(N_NODES + 64) * 4, stream);  // deg + cursor

  hist_kernel<<<(N_EDGES + 255) / 256, 256, 0, stream>>>(dstv, deg, epos,
                                                         Watt, Wt);
  qgemm_base_kernel<<<QGEMM_BLOCKS + BASE_BLOCKS, 256, 0, stream>>>(
      x, Wt, (uint2*)q_t, xhi, deg, cursor, offs2, csr2);
  scatter_kernel<<<(N_EDGES + 255) / 256, 256, 0, stream>>>(
      srcv, dstv, ew, offs2, epos, csr2);
  aggregate_kernel<<<N_NODES / 8, 256, 0, stream>>>(
      (const uint4*)q_t, (const uint4*)xhi, offs2, csr2, agg);
  out_gemm_kernel<<<(N_NODES + AGG_NODES - 1) / AGG_NODES, 256, 0, stream>>>(
      agg, Wlin, bias, out);
}

// Round 15
// 171.131 us; speedup vs baseline: 1.0607x; 1.0607x over previous
//
#include <hip/hip_runtime.h>
#include <hip/hip_bf16.h>
#include <math.h>

#define N_NODES 50000
#define N_EDGES 800000
#define GEMM_ROWS 32
#define AGG_NODES 32
#define PAD_EDGES (N_EDGES + N_NODES * 15)  // segments padded to x16
#define QGEMM_BLOCKS ((N_NODES + GEMM_ROWS - 1) / GEMM_ROWS)  // 1563
#define BASE_BLOCKS ((N_NODES + 255) / 256)                    // 196
// 0.125 (1/sqrt(64)) * log2(e): folded into Wt -> exp2 in the hot loop.
#define SCALE_FOLD 0.18033688011112042f
// u32 per LDS x-row. 34*4 = 136B pitch: staged via uint2 (136%8==0 OK),
// and makes the PV column reads (u16, stride 136B) bank-conflict-free:
// dword bank = (edge*34 + 8b + l15/2)%32 -> 16 banks, same-dword pairs only.
#define XT_STRIDE 34

typedef __attribute__((ext_vector_type(8))) short bf16x8_t;
typedef __attribute__((ext_vector_type(4))) float f32x4_t;

static __device__ __forceinline__ ushort bfrn(float v) {
  __hip_bfloat16 b = __float2bfloat16(v);  // round-to-nearest-even
  return __builtin_bit_cast(ushort, b);
}
static __device__ __forceinline__ bf16x8_t as_bf16x8(uint4 u) {
  union { uint4 a; bf16x8_t b; } c; c.a = u; return c.b;
}
static __device__ __forceinline__ float bflo(uint u) {
  return __uint_as_float(u << 16);
}
static __device__ __forceinline__ float bfhi(uint u) {
  return __uint_as_float(u & 0xFFFF0000u);
}

// ---------------------------------------------------------------------------
// K1: hist (degree + intra-segment position) + fused W_att^T transpose/scale.
// Wt[h*4096 + r*64 + c] = Watt[c*256 + h*64 + r] * SCALE_FOLD
// => q_t[i][h][c] = sum_r x_i[r]*Watt[c][h*64+r];  score = u[src].x[dst].
// ---------------------------------------------------------------------------
__global__ __launch_bounds__(256) void hist_kernel(
    const int* __restrict__ dst, int* __restrict__ deg, int* __restrict__ epos,
    const float* __restrict__ Watt, float* __restrict__ Wt) {
  int e = blockIdx.x * 256 + threadIdx.x;
  if (e < 16384) {
    int c = e & 63;
    int r = (e >> 6) & 63;
    int h = e >> 12;
    Wt[e] = Watt[c * 256 + h * 64 + r] * SCALE_FOLD;
  }
  if (e < N_EDGES) epos[e] = atomicAdd(&deg[dst[e]], 1);
}

// ---------------------------------------------------------------------------
// K2 (merged): qgemm tiles + per-node CSR base (wave-aggregated atomic).
// ---------------------------------------------------------------------------
__global__ __launch_bounds__(256) void qgemm_base_kernel(
    const float* __restrict__ x, const float* __restrict__ Wt,
    uint2* __restrict__ q_t2, ushort* __restrict__ xhi,
    const int* __restrict__ deg, int* __restrict__ cursor,
    int2* __restrict__ offs2, int2* __restrict__ csr2) {
  const int tid = threadIdx.x;
  if (blockIdx.x >= QGEMM_BLOCKS) {
    const int i = (blockIdx.x - QGEMM_BLOCKS) * 256 + tid;
    const int lane = tid & 63;
    const int d = (i < N_NODES) ? deg[i] : 0;
    const int nt = (d + 15) >> 4;
    const int pd = nt << 4;
    int incl = pd;
#pragma unroll
    for (int m = 1; m < 64; m <<= 1) {
      int u = __shfl_up(incl, m);
      if (lane >= m) incl += u;
    }
    int wbase = 0;
    if (lane == 63) wbase = atomicAdd(cursor, incl);
    wbase = __shfl(wbase, 63);
    const int base = wbase + incl - pd;
    if (i < N_NODES) {
      offs2[i] = make_int2(base, nt);
      for (int j = d; j < pd; ++j) csr2[base + j] = make_int2(0, 0);
    }
    return;
  }
  __shared__ float xlds[GEMM_ROWS * 64];
  const int blk = blockIdx.x;
#pragma unroll
  for (int p = 0; p < 8; ++p) {
    int idx = p * 256 + tid;
    int gidx = blk * (GEMM_ROWS * 64) + idx;
    xlds[idx] = (gidx < N_NODES * 64) ? x[gidx] : 0.f;
  }
  __syncthreads();
  {
    int row = tid >> 3;
    int c0 = (tid & 7) * 8;
    int grow = blk * GEMM_ROWS + row;
    if (grow < N_NODES) {
      uint hu[4];
#pragma unroll
      for (int d2 = 0; d2 < 4; ++d2) {
        float v0 = xlds[row * 64 + c0 + 2 * d2];
        float v1 = xlds[row * 64 + c0 + 2 * d2 + 1];
        hu[d2] = (uint)bfrn(v0) | ((uint)bfrn(v1) << 16);
      }
      *(uint4*)(xhi + (size_t)grow * 64 + c0) =
          make_uint4(hu[0], hu[1], hu[2], hu[3]);
    }
  }
  const int c4 = tid & 63;
  const int h = c4 >> 4;
  const int f4 = c4 & 15;
  const int rg = (tid >> 6) * 8;
  const float4* Wv = (const float4*)Wt;
  float4 acc[8] = {};
  for (int g = 0; g < 64; ++g) {
    float4 w4 = Wv[(size_t)h * 1024 + g * 16 + f4];
#pragma unroll
    for (int r = 0; r < 8; ++r) {
      float a = xlds[(rg + r) * 64 + g];
      acc[r].x += a * w4.x; acc[r].y += a * w4.y;
      acc[r].z += a * w4.z; acc[r].w += a * w4.w;
    }
  }
#pragma unroll
  for (int r = 0; r < 8; ++r) {
    int row = blk * GEMM_ROWS + rg + r;
    if (row < N_NODES) {
      uint2 pk;
      pk.x = (uint)bfrn(acc[r].x) | ((uint)bfrn(acc[r].y) << 16);
      pk.y = (uint)bfrn(acc[r].z) | ((uint)bfrn(acc[r].w) << 16);
      q_t2[(size_t)row * 64 + c4] = pk;  // ushort[row*256 + h*64 + 4f4..]
    }
  }
}

// ---------------------------------------------------------------------------
// K3: scatter edges into padded-CSR order (no atomics; single 8B write)
// ---------------------------------------------------------------------------
__global__ __launch_bounds__(256) void scatter_kernel(
    const int* __restrict__ src, const int* __restrict__ dst,
    const float* __restrict__ ew, const int2* __restrict__ offs2,
    const int* __restrict__ epos, int2* __restrict__ csr2) {
  int e = blockIdx.x * 256 + threadIdx.x;
  if (e >= N_EDGES) return;
  int idx = offs2[dst[e]].x + epos[e];
  csr2[idx] = make_int2(src[e], __float_as_int(ew[e]));
}

// ---------------------------------------------------------------------------
// K4: aggregation, one wave per node, 16-edge tiles.
// Scores (verified R11 path): 2x mfma_f32_16x16x32_bf16, A=q_t raw loads.
// NEW: PV also on MFMA. P rounded to bf16 -> plds_t[head][edge]; A-fragment
// of PV = 1x ds_read_b128 (lanes lg<2; lg>=2 feed zeros: K=32, 16 real
// edges). B-fragment = lane's feature column of the x-tile via 8 scalar u16
// LDS reads (XT_STRIDE=34 -> conflict-free). 4 PV MFMAs (feature blocks)
// + 1 ones-B MFMA gives the denominator free. D layout (m89): lane(l15,lg)
// reg r = D[row 4lg+r][col l15]; dup-A rows make reg r = head r on EVERY
// lane -> epilogue = cndmask select + 4 coalesced u16 stores, no shuffles.
// ---------------------------------------------------------------------------
__global__ __launch_bounds__(256) void aggregate_kernel(
    const uint4* __restrict__ qt4, const uint4* __restrict__ xhi4,
    const int2* __restrict__ offs2, const int2* __restrict__ csr2,
    ushort* __restrict__ agg) {
  __shared__ __attribute__((aligned(16))) ushort xt16[4][16][XT_STRIDE * 2];
  __shared__ __attribute__((aligned(16))) ushort pt[4][4][16];  // [head][edge]
  const int wave = threadIdx.x >> 6;
  const int node = blockIdx.x * 4 + wave;  // grid exact: 50000 = 4*12500
  const int lane = threadIdx.x & 63;
  const int l15 = lane & 15;
  const int lg = lane >> 4;
  const int hq = l15 & 3;

  const bf16x8_t Qa = as_bf16x8(qt4[(size_t)node * 32 + hq * 8 + lg]);
  const bf16x8_t Qb = as_bf16x8(qt4[(size_t)node * 32 + hq * 8 + 4 + lg]);
  const int2 o2 = offs2[node];
  const int s0 = o2.x;
  const int ntiles = o2.y;

  const bf16x8_t ONES =
      as_bf16x8(make_uint4(0x3F803F80u, 0x3F803F80u, 0x3F803F80u, 0x3F803F80u));
  f32x4_t acc0 = {0.f, 0.f, 0.f, 0.f};
  f32x4_t acc1 = {0.f, 0.f, 0.f, 0.f};
  f32x4_t acc2 = {0.f, 0.f, 0.f, 0.f};
  f32x4_t acc3 = {0.f, 0.f, 0.f, 0.f};
  f32x4_t accL = {0.f, 0.f, 0.f, 0.f};

  const int eb = (lg & 1) * 8;  // B-fragment edge base (lg>=2 reuses 0..15)

  for (int t = 0; t < ntiles; ++t) {
    const int k0 = s0 + t * 16;
    const int2 e2 = csr2[k0 + l15];
    const int j = e2.x;
    const float w = __int_as_float(e2.y);
    const uint4 ah0 = xhi4[(size_t)j * 8 + lg];      // feats 8lg..8lg+7
    const uint4 ah1 = xhi4[(size_t)j * 8 + 4 + lg];  // feats 32+8lg..+7
    // stage x row (bf16) at 136B pitch via uint2 (8B-aligned)
    {
      ushort* xr = &xt16[wave][l15][0];
      *(uint2*)(xr + 8 * lg) = make_uint2(ah0.x, ah0.y);
      *(uint2*)(xr + 8 * lg + 4) = make_uint2(ah0.z, ah0.w);
      *(uint2*)(xr + 32 + 8 * lg) = make_uint2(ah1.x, ah1.y);
      *(uint2*)(xr + 32 + 8 * lg + 4) = make_uint2(ah1.z, ah1.w);
    }
    // scores: S[head reg][edge l15]
    f32x4_t S = {0.f, 0.f, 0.f, 0.f};
    S = __builtin_amdgcn_mfma_f32_16x16x32_bf16(Qa, as_bf16x8(ah0), S, 0, 0, 0);
    S = __builtin_amdgcn_mfma_f32_16x16x32_bf16(Qb, as_bf16x8(ah1), S, 0, 0, 0);
    // p = exp2(leaky(s)) * w -> bf16 -> pt[head][edge]
    float p0 = exp2f(fmaxf(S[0], 0.2f * S[0])) * w;
    float p1 = exp2f(fmaxf(S[1], 0.2f * S[1])) * w;
    float p2 = exp2f(fmaxf(S[2], 0.2f * S[2])) * w;
    float p3 = exp2f(fmaxf(S[3], 0.2f * S[3])) * w;
    if (lg == 0) {
      pt[wave][0][l15] = bfrn(p0);
      pt[wave][1][l15] = bfrn(p1);
      pt[wave][2][l15] = bfrn(p2);
      pt[wave][3][l15] = bfrn(p3);
    }
    // PV A-fragment: P[head l15&3][edge 8lg+i]; lg>=2 -> zero (k 16..31 pad)
    uint4 pau = make_uint4(0u, 0u, 0u, 0u);
    if (lg < 2) pau = *(const uint4*)&pt[wave][hq][8 * lg];
    const bf16x8_t pa = as_bf16x8(pau);
    // PV B-fragments: lane's feature column 16b+l15 across edges eb..eb+7
#pragma unroll
    for (int b = 0; b < 4; ++b) {
      const int fc = 16 * b + l15;
      uint bw0 = (uint)xt16[wave][eb + 0][fc] |
                 ((uint)xt16[wave][eb + 1][fc] << 16);
      uint bw1 = (uint)xt16[wave][eb + 2][fc] |
                 ((uint)xt16[wave][eb + 3][fc] << 16);
      uint bw2 = (uint)xt16[wave][eb + 4][fc] |
                 ((uint)xt16[wave][eb + 5][fc] << 16);
      uint bw3 = (uint)xt16[wave][eb + 6][fc] |
                 ((uint)xt16[wave][eb + 7][fc] << 16);
      const bf16x8_t bx = as_bf16x8(make_uint4(bw0, bw1, bw2, bw3));
      if (b == 0)
        acc0 = __builtin_amdgcn_mfma_f32_16x16x32_bf16(pa, bx, acc0, 0, 0, 0);
      else if (b == 1)
        acc1 = __builtin_amdgcn_mfma_f32_16x16x32_bf16(pa, bx, acc1, 0, 0, 0);
      else if (b == 2)
        acc2 = __builtin_amdgcn_mfma_f32_16x16x32_bf16(pa, bx, acc2, 0, 0, 0);
      else
        acc3 = __builtin_amdgcn_mfma_f32_16x16x32_bf16(pa, bx, acc3, 0, 0, 0);
    }
    accL = __builtin_amdgcn_mfma_f32_16x16x32_bf16(pa, ONES, accL, 0, 0, 0);
  }

  // epilogue: every lane holds heads 0-3 (reg r) of feats {16b + l15};
  // lane (l15, lg) writes head lg.
  const float lpv = (lg == 0) ? accL[0]
                  : (lg == 1) ? accL[1]
                  : (lg == 2) ? accL[2] : accL[3];
  const float inv = 1.f / (lpv + 1e-16f);
  const float v0 = ((lg == 0) ? acc0[0] : (lg == 1) ? acc0[1]
                   : (lg == 2) ? acc0[2] : acc0[3]) * inv;
  const float v1 = ((lg == 0) ? acc1[0] : (lg == 1) ? acc1[1]
                   : (lg == 2) ? acc1[2] : acc1[3]) * inv;
  const float v2 = ((lg == 0) ? acc2[0] : (lg == 1) ? acc2[1]
                   : (lg == 2) ? acc2[2] : acc2[3]) * inv;
  const float v3 = ((lg == 0) ? acc3[0] : (lg == 1) ? acc3[1]
                   : (lg == 2) ? acc3[2] : acc3[3]) * inv;
  ushort* ap = agg + (size_t)node * 256 + lg * 64 + l15;
  ap[0] = bfrn(v0);
  ap[16] = bfrn(v1);
  ap[32] = bfrn(v2);
  ap[48] = bfrn(v3);
}

// ---------------------------------------------------------------------------
// K5: out[n, :] = agg(bf16)[n, block-diag] @ Wlin + bias. 32 nodes/block.
// ---------------------------------------------------------------------------
__global__ __launch_bounds__(256) void out_gemm_kernel(
    const ushort* __restrict__ agg, const float* __restrict__ Wlin,
    const float* __restrict__ bias, float* __restrict__ out) {
  __shared__ float4 atile[AGG_NODES][4][17];
  const int tid = threadIdx.x;
  const int node0 = blockIdx.x * AGG_NODES;
  const uint2* av = (const uint2*)agg;
#pragma unroll
  for (int p = 0; p < 8; ++p) {
    int idx = p * 256 + tid;
    int row = idx >> 6;
    int cc = idx & 63;
    if (node0 + row < N_NODES) {
      uint2 u = av[(size_t)(node0 + row) * 64 + cc];
      float4 f;
      f.x = bflo(u.x); f.y = bfhi(u.x);
      f.z = bflo(u.y); f.w = bfhi(u.y);
      atile[row][cc >> 4][cc & 15] = f;
    }
  }
  __syncthreads();
  const int c4 = tid & 63;
  const int ns = tid >> 6;
  const int hh = c4 >> 4;
  const float4* Wv = (const float4*)Wlin;
  float4 acc[8] = {};
  for (int g4 = 0; g4 < 16; ++g4) {
    float4 w0 = Wv[(size_t)(g4 * 4 + 0) * 64 + c4];
    float4 w1 = Wv[(size_t)(g4 * 4 + 1) * 64 + c4];
    float4 w2 = Wv[(size_t)(g4 * 4 + 2) * 64 + c4];
    float4 w3 = Wv[(size_t)(g4 * 4 + 3) * 64 + c4];
#pragma unroll
    for (int n = 0; n < 8; ++n) {
      float4 a = atile[ns * 8 + n][hh][g4];
      acc[n].x += a.x * w0.x + a.y * w1.x + a.z * w2.x + a.w * w3.x;
      acc[n].y += a.x * w0.y + a.y * w1.y + a.z * w2.y + a.w * w3.y;
      acc[n].z += a.x * w0.z + a.y * w1.z + a.z * w2.z + a.w * w3.z;
      acc[n].w += a.x * w0.w + a.y * w1.w + a.z * w2.w + a.w * w3.w;
    }
  }
  float4 bv = ((const float4*)bias)[c4];
#pragma unroll
  for (int n = 0; n < 8; ++n) {
    int node = node0 + ns * 8 + n;
    if (node < N_NODES) {
      float4 o;
      o.x = acc[n].x + bv.x; o.y = acc[n].y + bv.y;
      o.z = acc[n].z + bv.z; o.w = acc[n].w + bv.w;
      ((float4*)out)[(size_t)node * 64 + c4] = o;
    }
  }
}

// ---------------------------------------------------------------------------
extern "C" void kernel_launch(void* const* d_in, const int* in_sizes, int n_in,
                              void* d_out, int out_size, void* d_ws,
                              size_t ws_size, hipStream_t stream) {
  (void)in_sizes; (void)n_in; (void)out_size; (void)ws_size;
  const float* x    = (const float*)d_in[0];
  const int*   ei   = (const int*)d_in[1];
  const float* ew   = (const float*)d_in[2];
  const float* Wlin = (const float*)d_in[3];
  const float* Watt = (const float*)d_in[4];
  const float* bias = (const float*)d_in[5];
  float* out = (float*)d_out;

  const int* srcv = ei;
  const int* dstv = ei + N_EDGES;

  char* ws = (char*)d_ws;
  size_t off = 0;
  auto alloc = [&](size_t bytes) {
    void* p = ws + off;
    off += (bytes + 255) & ~(size_t)255;
    return p;
  };
  ushort* q_t   = (ushort*)alloc((size_t)N_NODES * 256 * 2);  // 25.6 MB
  ushort* agg   = (ushort*)alloc((size_t)N_NODES * 256 * 2);  // 25.6 MB
  ushort* xhi   = (ushort*)alloc((size_t)N_NODES * 64 * 2);   // 6.4 MB
  int2*   offs2 = (int2*)alloc((size_t)N_NODES * 8);          // 0.4 MB
  int2*   csr2  = (int2*)alloc((size_t)PAD_EDGES * 8);        // 12.4 MB
  // aliases inside agg (all dead before aggregate_kernel writes agg):
  char* aggc = (char*)agg;
  int*   deg    = (int*)aggc;                       // 200 KB (dead after base)
  int*   cursor = (int*)(aggc + N_NODES * 4);       // 4 B    (dead after base)
  int*   epos   = (int*)(aggc + 256 * 1024);        // 3.2 MB (dead after scatter)
  float* Wt     = (float*)(aggc + 4 * 1024 * 1024); // 64 KB  (dead after qgemm)

  hipMemsetAsync(deg, 0, (size_t)(N_NODES + 64) * 4, stream);  // deg + cursor

  hist_kernel<<<(N_EDGES + 255) / 256, 256, 0, stream>>>(dstv, deg, epos,
                                                         Watt, Wt);
  qgemm_base_kernel<<<QGEMM_BLOCKS + BASE_BLOCKS, 256, 0, stream>>>(
      x, Wt, (uint2*)q_t, xhi, deg, cursor, offs2, csr2);
  scatter_kernel<<<(N_EDGES + 255) / 256, 256, 0, stream>>>(
      srcv, dstv, ew, offs2, epos, csr2);
  aggregate_kernel<<<N_NODES / 4, 256, 0, stream>>>(
      (const uint4*)q_t, (const uint4*)xhi, offs2, csr2, agg);
  out_gemm_kernel<<<(N_NODES + AGG_NODES - 1) / AGG_NODES, 256, 0, stream>>>(
      agg, Wlin, bias, out);
}